// Round 12
// baseline (814.774 us; speedup 1.0000x reference)
//
#include <hip/hip_runtime.h>
#include <hip/hip_bf16.h>

// Problem constants
#define BB 8
#define SS 2048
#define DD 256
#define HH 512
#define LL 3
#define NROWS (BB * SS)
#define NWRK 8            // head worker blocks (one per batch row)
#define NSTB (NROWS / 4)  // store blocks (4 rows each)

typedef float floatx4 __attribute__((ext_vector_type(4)));

// ---------------------------------------------------------------------------
// Kernel 0: M[k][t] = sum_d proj_w[d][k]*pe[d][t]; c = pb . pe
// Mc layout: interleaved [k*2+t] (512 floats), then c0,c1 at [512],[513]
// ---------------------------------------------------------------------------
__global__ void compute_M(const float* __restrict__ pw, const float* __restrict__ pb,
                          const float* __restrict__ pe, float* __restrict__ Mc)
{
    __shared__ float s0[4][256], s1[4][256];
    int tid = threadIdx.x;
    int k = tid & 255;
    int sub = tid >> 8;
    float a0 = 0.f, a1 = 0.f;
    #pragma unroll 8
    for (int d = sub * 64; d < sub * 64 + 64; ++d) {
        float w = pw[d * DD + k];
        a0 += w * pe[2 * d];
        a1 += w * pe[2 * d + 1];
    }
    s0[sub][k] = a0;
    s1[sub][k] = a1;
    __syncthreads();
    if (tid < 256) {
        Mc[2 * tid]     = s0[0][tid] + s0[1][tid] + s0[2][tid] + s0[3][tid];
        Mc[2 * tid + 1] = s1[0][tid] + s1[1][tid] + s1[2][tid] + s1[3][tid];
    }
    if (tid < 64) {
        float c0 = 0.f, c1 = 0.f;
        for (int d = tid; d < DD; d += 64) {
            c0 += pb[d] * pe[2 * d];
            c1 += pb[d] * pe[2 * d + 1];
        }
        #pragma unroll
        for (int dd = 32; dd; dd >>= 1) {
            c0 += __shfl_xor(c0, dd);
            c1 += __shfl_xor(c1, dd);
        }
        if (tid == 0) { Mc[512] = c0; Mc[513] = c1; }
    }
}

// ---------------------------------------------------------------------------
// Kernel 1: psi = normalize(x @ M + c) then 7 diffusion rescales (force==0).
// One wave per row; each wave does 4 rows.
// ---------------------------------------------------------------------------
__global__ void psi_kernel(const float* __restrict__ x, const float* __restrict__ Mc,
                           float* __restrict__ psi)
{
    int tid = threadIdx.x;
    int wave = tid >> 6, lane = tid & 63;
    const float4* Mc4 = reinterpret_cast<const float4*>(Mc);
    float4 mA = Mc4[lane * 2];
    float4 mB = Mc4[lane * 2 + 1];
    float c0 = Mc[512], c1 = Mc[513];
    int base = blockIdx.x * 16 + wave * 4;
    #pragma unroll
    for (int it = 0; it < 4; ++it) {
        int rid = base + it;
        float4 v = *reinterpret_cast<const float4*>(x + (size_t)rid * DD + lane * 4);
        float a0 = v.x * mA.x + v.y * mA.z + v.z * mB.x + v.w * mB.z;
        float a1 = v.x * mA.y + v.y * mA.w + v.z * mB.y + v.w * mB.w;
        #pragma unroll
        for (int d = 32; d; d >>= 1) {
            a0 += __shfl_xor(a0, d);
            a1 += __shfl_xor(a1, d);
        }
        a0 += c0;
        a1 += c1;
        float n = sqrtf(a0 * a0 + a1 * a1);
        float scale = 1.f / (n + 1e-8f);
        float r = n * scale;
        #pragma unroll
        for (int i7 = 0; i7 < 7; ++i7) {
            float f = r / (r + 1e-8f);
            scale *= f;
            r *= f;
        }
        if (lane == 0) {
            float2 pv;
            pv.x = a0 * scale;
            pv.y = a1 * scale;
            *reinterpret_cast<float2*>(psi + (size_t)rid * 2) = pv;
        }
    }
}

// ---------------------------------------------------------------------------
// Block-local LN: out[k] = (in[k]-mean)*rstd*w[k]+b[k], N elems, in-place OK.
// ---------------------------------------------------------------------------
__device__ __forceinline__ void ln_blk(const float* in, int N,
                                       const float* __restrict__ w,
                                       const float* __restrict__ bvec,
                                       float* out, float* s_stat, int tid)
{
    if (tid < 64) {
        float s = 0.f, ss = 0.f;
        for (int k = tid; k < N; k += 64) {
            float v = in[k];
            s += v; ss += v * v;
        }
        #pragma unroll
        for (int d = 32; d; d >>= 1) {
            s += __shfl_xor(s, d);
            ss += __shfl_xor(ss, d);
        }
        if (tid == 0) {
            float m = s / N;
            s_stat[0] = m;
            s_stat[1] = rsqrtf(ss / N - m * m + 1e-5f);
        }
    }
    __syncthreads();
    float m = s_stat[0], r = s_stat[1];
    for (int k = tid; k < N; k += 1024)
        out[k] = (in[k] - m) * r * w[k] + bvec[k];
    __syncthreads();
}

// ---------------------------------------------------------------------------
// Block-local GEMV-batch: outLDS[j] = res?[j] + act(bias[j] + sXin . W[j,:])
// G lanes per output (power of 2, within-wave), 1024 threads.
// ---------------------------------------------------------------------------
__device__ __forceinline__ void bgemm(const float* sXin, int K,
                                      const float* __restrict__ W,
                                      const float* __restrict__ bias,
                                      const float* resLDS, float* outLDS,
                                      int J, int G, int act, int tid)
{
    const int g = tid & (G - 1);
    const int K4 = K >> 2;
    const float4* X4 = reinterpret_cast<const float4*>(sXin);
    for (int j = tid / G; j < J; j += 1024 / G) {
        const float4* W4 = reinterpret_cast<const float4*>(W + (size_t)j * K);
        float acc = 0.f;
        for (int i4 = g; i4 < K4; i4 += G) {
            float4 w = W4[i4];
            float4 xv = X4[i4];
            acc = fmaf(w.x, xv.x, acc);
            acc = fmaf(w.y, xv.y, acc);
            acc = fmaf(w.z, xv.z, acc);
            acc = fmaf(w.w, xv.w, acc);
        }
        for (int d = G >> 1; d; d >>= 1) acc += __shfl_xor(acc, d);
        if (g == 0) {
            float v = acc + bias[j];
            if (act) v = v / (1.f + expf(-v));   // silu
            if (resLDS) v += resLDS[j];
            outLDS[j] = v;
        }
    }
    __syncthreads();
}

// ---------------------------------------------------------------------------
// Mega kernel: blocks 0..7 = per-b head chain (all-LDS, no global activations)
//              blocks 8..  = A/mask rows (4 per block), NT stores
// ---------------------------------------------------------------------------
__global__ void __launch_bounds__(1024) mega(
    const float* __restrict__ psi, const float* __restrict__ hebb,
    const float* __restrict__ ai_w, const float* __restrict__ ai_b,
    const float* __restrict__ ao_w, const float* __restrict__ ao_b,
    const float* __restrict__ f1_w, const float* __restrict__ f1_b,
    const float* __restrict__ f2_w, const float* __restrict__ f2_b,
    const float* __restrict__ ln1w, const float* __restrict__ ln1b,
    const float* __restrict__ ln2w, const float* __restrict__ ln2b,
    const float* __restrict__ nAw, const float* __restrict__ nAb,
    const float* __restrict__ nBw, const float* __restrict__ nBb,
    const float* __restrict__ p1w, const float* __restrict__ p1b,
    const float* __restrict__ p2w, const float* __restrict__ p2b,
    float* __restrict__ preds, float* __restrict__ A, float* __restrict__ Mask)
{
    const int bid = blockIdx.x;
    const int tid = threadIdx.x;

    if (bid >= NWRK) {
        // ---- store blocks: 4 rows each, 256-thread sub-groups ----
        int srow = tid >> 8, stid = tid & 255;
        int blk = (bid - NWRK) * 4 + srow;
        int b = blk >> 11, i = blk & (SS - 1);
        float2 pi = *reinterpret_cast<const float2*>(psi + (size_t)blk * 2);
        #pragma unroll
        for (int c = 0; c < 2; ++c) {
            int j0 = c * 1024 + stid * 4;
            const float4* pr = reinterpret_cast<const float4*>(psi + ((size_t)b * SS + j0) * 2);
            float4 q0 = pr[0], q1 = pr[1];
            floatx4 o;
            o.x = pi.x * q0.x + pi.y * q0.y;
            o.y = pi.x * q0.z + pi.y * q0.w;
            o.z = pi.x * q1.x + pi.y * q1.y;
            o.w = pi.x * q1.z + pi.y * q1.w;
            size_t rb = (size_t)blk * SS + j0;
            __builtin_nontemporal_store(o, reinterpret_cast<floatx4*>(A + rb));
            floatx4 m;
            m.x = (i == j0    ) ? 1.f : 0.f;
            m.y = (i == j0 + 1) ? 1.f : 0.f;
            m.z = (i == j0 + 2) ? 1.f : 0.f;
            m.w = (i == j0 + 3) ? 1.f : 0.f;
            __builtin_nontemporal_store(m, reinterpret_cast<floatx4*>(Mask + rb));
        }
        return;
    }

    // ---- worker block: full head chain for batch row b ----
    __shared__ __align__(16) float sT[HH];       // pre-LN state
    __shared__ __align__(16) float sX0[HH];      // LN'd input / x1
    __shared__ __align__(16) float sV[HH];
    __shared__ __align__(16) float sF[4 * HH];
    __shared__ __align__(16) float sP[HH / 2];
    __shared__ float s_stat[2];
    const int b = bid;

    // h0 = psi[b,S-1] . hebb^T
    {
        float2 pv = *reinterpret_cast<const float2*>(psi + ((size_t)b * SS + SS - 1) * 2);
        for (int j = tid; j < HH; j += 1024)
            sT[j] = pv.x * hebb[2 * j] + pv.y * hebb[2 * j + 1];
    }
    __syncthreads();

    for (int l = 0; l < LL; ++l) {
        // X0 = l ? LN(T, ln2[l-1]) : T
        if (l) {
            ln_blk(sT, HH, ln2w + (l - 1) * HH, ln2b + (l - 1) * HH, sX0, s_stat, tid);
        } else {
            for (int k = tid; k < HH; k += 1024) sX0[k] = sT[k];
            __syncthreads();
        }
        // v = X0 @ Wv^T + bv
        bgemm(sX0, HH, ai_w + ((size_t)l * 3 * HH + 2 * HH) * HH,
              ai_b + l * 3 * HH + 2 * HH, nullptr, sV, HH, 2, 0, tid);
        // t1 = X0 + (v @ Wo^T + bo)  -> sT
        bgemm(sV, HH, ao_w + (size_t)l * HH * HH, ao_b + l * HH,
              sX0, sT, HH, 2, 0, tid);
        // x1 = LN(t1, ln1[l]) -> sX0
        ln_blk(sT, HH, ln1w + l * HH, ln1b + l * HH, sX0, s_stat, tid);
        // f = silu(x1 @ W1^T + b1) -> sF
        bgemm(sX0, HH, f1_w + (size_t)l * 4 * HH * HH, f1_b + l * 4 * HH,
              nullptr, sF, 4 * HH, 1, 1, tid);
        // T = x1 + f @ W2^T + b2 -> sT
        bgemm(sF, 4 * HH, f2_w + (size_t)l * HH * 4 * HH, f2_b + l * HH,
              sX0, sT, HH, 2, 0, tid);
    }
    // xA = LN(LN(T, ln2[2]), normA)
    ln_blk(sT, HH, ln2w + 2 * HH, ln2b + 2 * HH, sX0, s_stat, tid);
    ln_blk(sX0, HH, nAw, nAb, sX0, s_stat, tid);
    // p = silu(xA @ p1^T + p1b)
    bgemm(sX0, HH, p1w, p1b, nullptr, sP, HH / 2, 4, 1, tid);
    // pB = LN(p, normB)
    ln_blk(sP, HH / 2, nBw, nBb, sP, s_stat, tid);
    // preds[b] = pB . p2w + p2b
    if (tid < 64) {
        float s = 0.f;
        for (int k = tid; k < HH / 2; k += 64) s += sP[k] * p2w[k];
        #pragma unroll
        for (int d = 32; d; d >>= 1) s += __shfl_xor(s, d);
        if (tid == 0) preds[b] = s + p2b[0];
    }
}

// ---------------------------------------------------------------------------
extern "C" void kernel_launch(void* const* d_in, const int* in_sizes, int n_in,
                              void* d_out, int out_size, void* d_ws, size_t ws_size,
                              hipStream_t stream)
{
    const float* x      = (const float*)d_in[0];
    const float* proj_w = (const float*)d_in[1];
    const float* proj_b = (const float*)d_in[2];
    const float* pe     = (const float*)d_in[3];
    const float* hebb   = (const float*)d_in[4];
    const float* ai_w   = (const float*)d_in[5];
    const float* ai_b   = (const float*)d_in[6];
    const float* ao_w   = (const float*)d_in[7];
    const float* ao_b   = (const float*)d_in[8];
    const float* f1_w   = (const float*)d_in[9];
    const float* f1_b   = (const float*)d_in[10];
    const float* f2_w   = (const float*)d_in[11];
    const float* f2_b   = (const float*)d_in[12];
    const float* ln1w   = (const float*)d_in[13];
    const float* ln1b   = (const float*)d_in[14];
    const float* ln2w   = (const float*)d_in[15];
    const float* ln2b   = (const float*)d_in[16];
    const float* nAw    = (const float*)d_in[17];
    const float* nAb    = (const float*)d_in[18];
    const float* nBw    = (const float*)d_in[19];
    const float* nBb    = (const float*)d_in[20];
    const float* p1w    = (const float*)d_in[21];
    const float* p1b    = (const float*)d_in[22];
    const float* p2w    = (const float*)d_in[23];
    const float* p2b    = (const float*)d_in[24];

    float* out   = (float*)d_out;
    // output layout: preds(8) | A(B*S*S) | mask(B*S*S) | psi(B*S*2)
    float* preds = out;
    float* A     = out + 8;
    float* Mask  = out + 8 + (size_t)BB * SS * SS;
    float* Psi   = out + 8 + (size_t)2 * BB * SS * SS;

    float* ws = (float*)d_ws;
    float* Mc = ws;            // 514 floats

    compute_M<<<1, 1024, 0, stream>>>(proj_w, proj_b, pe, Mc);
    psi_kernel<<<NROWS / 16, 256, 0, stream>>>(x, Mc, Psi);
    mega<<<NWRK + NSTB, 1024, 0, stream>>>(
        Psi, hebb, ai_w, ai_b, ao_w, ao_b, f1_w, f1_b, f2_w, f2_b,
        ln1w, ln1b, ln2w, ln2b, nAw, nAb, nBw, nBb, p1w, p1b, p2w, p2b,
        preds, A, Mask);
}

// Round 13
// 313.573 us; speedup vs baseline: 2.5984x; 2.5984x over previous
//
#include <hip/hip_runtime.h>
#include <hip/hip_bf16.h>

// Problem constants
#define BB 8
#define SS 2048
#define DD 256
#define HH 512
#define LL 3
#define NROWS (BB * SS)

typedef float floatx4 __attribute__((ext_vector_type(4)));

// ---------------------------------------------------------------------------
// A/mask row worker (NT stores; verified)
// ---------------------------------------------------------------------------
__device__ __forceinline__ void amask_row(const float* __restrict__ psi,
                                          float* __restrict__ A, float* __restrict__ M,
                                          int blk)
{
    int tid = threadIdx.x;
    int b = blk >> 11, i = blk & (SS - 1);
    float2 pi = *reinterpret_cast<const float2*>(psi + (size_t)blk * 2);
    #pragma unroll
    for (int c = 0; c < 2; ++c) {
        int j0 = c * 1024 + tid * 4;
        const float4* pr = reinterpret_cast<const float4*>(psi + ((size_t)b * SS + j0) * 2);
        float4 q0 = pr[0], q1 = pr[1];
        floatx4 o;
        o.x = pi.x * q0.x + pi.y * q0.y;
        o.y = pi.x * q0.z + pi.y * q0.w;
        o.z = pi.x * q1.x + pi.y * q1.y;
        o.w = pi.x * q1.z + pi.y * q1.w;
        size_t rb = (size_t)blk * SS + j0;
        __builtin_nontemporal_store(o, reinterpret_cast<floatx4*>(A + rb));
        floatx4 m;
        m.x = (i == j0    ) ? 1.f : 0.f;
        m.y = (i == j0 + 1) ? 1.f : 0.f;
        m.z = (i == j0 + 2) ? 1.f : 0.f;
        m.w = (i == j0 + 3) ? 1.f : 0.f;
        __builtin_nontemporal_store(m, reinterpret_cast<floatx4*>(M + rb));
    }
}

// ---------------------------------------------------------------------------
// Launch 1: per-block M in LDS -> psi (16 rows/block) ; h0 -> Tbase
// ---------------------------------------------------------------------------
__global__ void psiM_kernel(const float* __restrict__ x,
                            const float* __restrict__ pw, const float* __restrict__ pb,
                            const float* __restrict__ pe, const float* __restrict__ hebb,
                            float* __restrict__ psi, float* __restrict__ Tbase)
{
    __shared__ __align__(16) float sM[516];
    const int tid = threadIdx.x;
    const int bid = blockIdx.x;

    {   // M[k][t] for k=tid; coalesced pw reads, broadcast pe
        float a0 = 0.f, a1 = 0.f;
        for (int d = 0; d < DD; ++d) {
            float w = pw[d * DD + tid];
            a0 += w * pe[2 * d];
            a1 += w * pe[2 * d + 1];
        }
        sM[2 * tid] = a0;
        sM[2 * tid + 1] = a1;
    }
    if (tid < 64) {
        float c0 = 0.f, c1 = 0.f;
        for (int d = tid; d < DD; d += 64) {
            c0 += pb[d] * pe[2 * d];
            c1 += pb[d] * pe[2 * d + 1];
        }
        #pragma unroll
        for (int dd = 32; dd; dd >>= 1) {
            c0 += __shfl_xor(c0, dd);
            c1 += __shfl_xor(c1, dd);
        }
        if (tid == 0) { sM[512] = c0; sM[513] = c1; }
    }
    __syncthreads();

    int wave = tid >> 6, lane = tid & 63;
    const float4* sM4 = reinterpret_cast<const float4*>(sM);
    float4 mA = sM4[lane * 2];
    float4 mB = sM4[lane * 2 + 1];
    float c0 = sM[512], c1 = sM[513];
    int base = bid * 16 + wave * 4;
    #pragma unroll
    for (int it = 0; it < 4; ++it) {
        int rid = base + it;
        float4 v = *reinterpret_cast<const float4*>(x + (size_t)rid * DD + lane * 4);
        float a0 = v.x * mA.x + v.y * mA.z + v.z * mB.x + v.w * mB.z;
        float a1 = v.x * mA.y + v.y * mA.w + v.z * mB.y + v.w * mB.w;
        #pragma unroll
        for (int d = 32; d; d >>= 1) {
            a0 += __shfl_xor(a0, d);
            a1 += __shfl_xor(a1, d);
        }
        a0 += c0;
        a1 += c1;
        float n = sqrtf(a0 * a0 + a1 * a1);
        float scale = 1.f / (n + 1e-8f);
        float r = n * scale;
        #pragma unroll
        for (int i7 = 0; i7 < 7; ++i7) {
            float f = r / (r + 1e-8f);
            scale *= f;
            r *= f;
        }
        float px = a0 * scale, py = a1 * scale;
        if (lane == 0) {
            float2 pv;
            pv.x = px;
            pv.y = py;
            *reinterpret_cast<float2*>(psi + (size_t)rid * 2) = pv;
        }
        if ((rid & (SS - 1)) == SS - 1) {   // h0 -> Tbase
            int b = rid >> 11;
            for (int j = lane; j < HH; j += 64)
                Tbase[(size_t)b * HH + j] = px * hebb[2 * j] + py * hebb[2 * j + 1];
        }
    }
}

// ---------------------------------------------------------------------------
// Per-row LN for [8][N] in LDS: stats per row (32 lanes/row), then apply.
// sh = log2(N). In-place safe.
// ---------------------------------------------------------------------------
__device__ __forceinline__ void ln8(const float* in, float* out, int N, int sh,
                                    const float* __restrict__ w,
                                    const float* __restrict__ bvec,
                                    float* s_m, float* s_r, int tid)
{
    int row = tid >> 5, lane = tid & 31;
    float s = 0.f, ss = 0.f;
    for (int k = lane; k < N; k += 32) {
        float v = in[(row << sh) + k];
        s += v; ss += v * v;
    }
    #pragma unroll
    for (int d = 16; d; d >>= 1) { s += __shfl_down(s, d); ss += __shfl_down(ss, d); }
    if (lane == 0) {
        float m = s / N;
        s_m[row] = m;
        s_r[row] = rsqrtf(ss / N - m * m + 1e-5f);
    }
    __syncthreads();
    for (int idx = tid; idx < (N << 3); idx += 256) {
        int b = idx >> sh, k = idx & (N - 1);
        out[idx] = (in[idx] - s_m[b]) * s_r[b] * w[k] + bvec[k];
    }
    __syncthreads();
}

// ---------------------------------------------------------------------------
// Carrier kernel. mode 0 = VO (8 mm blocks), 1 = FF (16 mm blocks),
// 2 = tail (1 mm block). Blocks >= nmm stream A/mask rows.
// Cross-launch handoff: Tbase/t1base + vpart/fpart partial-sum buffers.
// ---------------------------------------------------------------------------
__global__ void __launch_bounds__(256) carrier(
    int mode, int l, int nmm, int arow0,
    const float* __restrict__ psi,
    const float* __restrict__ ai_w, const float* __restrict__ ai_b,
    const float* __restrict__ ao_w, const float* __restrict__ ao_b,
    const float* __restrict__ f1_w, const float* __restrict__ f1_b,
    const float* __restrict__ f2_w, const float* __restrict__ f2_b,
    const float* __restrict__ ln1w, const float* __restrict__ ln1b,
    const float* __restrict__ ln2w, const float* __restrict__ ln2b,
    const float* __restrict__ nAw, const float* __restrict__ nAb,
    const float* __restrict__ nBw, const float* __restrict__ nBb,
    const float* __restrict__ p1w, const float* __restrict__ p1b,
    const float* __restrict__ p2w, const float* __restrict__ p2b,
    float* __restrict__ Tbase, float* __restrict__ t1base,
    float* __restrict__ vpart, float* __restrict__ fpart,
    float* __restrict__ preds, float* __restrict__ A, float* __restrict__ Mask)
{
    const int bid = blockIdx.x;
    const int tid = threadIdx.x;
    if (bid >= nmm) {
        int r = arow0 + (bid - nmm);
        if (r < NROWS) amask_row(psi, A, Mask, r);
        return;
    }

    __shared__ __align__(16) float sT[8 * HH];
    __shared__ __align__(16) float sX[8 * HH];
    __shared__ __align__(16) float sS[8 * 256];
    __shared__ float s_m[8], s_r[8];
    const float4* sX4 = reinterpret_cast<const float4*>(sX);

    if (mode == 0) {
        // ---------------- VO: t1 = X0 + X0@Wv@Wo^T (+bv folded) ------------
        // reconstruct T_l
        if (l == 0) {
            for (int idx = tid; idx < 4096; idx += 256) sT[idx] = Tbase[idx];
        } else {
            for (int idx = tid; idx < 4096; idx += 256) {
                float v = Tbase[idx];
                #pragma unroll 4
                for (int q = 0; q < 16; ++q) v += fpart[q * 4096 + idx];
                sT[idx] = v;
            }
        }
        __syncthreads();
        const float* x0;
        if (l) {
            ln8(sT, sX, HH, 9, ln2w + (l - 1) * HH, ln2b + (l - 1) * HH, s_m, s_r, tid);
            x0 = sX;
        } else {
            x0 = sT;
        }
        const float4* x04 = reinterpret_cast<const float4*>(x0);
        // v slice: 64 outputs, G=4
        {
            int jj = tid >> 2, g = tid & 3;
            int j = bid * 64 + jj;
            float acc[8] = {0,0,0,0,0,0,0,0};
            const float4* Wv4 = reinterpret_cast<const float4*>(
                ai_w + ((size_t)l * 3 * HH + 2 * HH) * HH + (size_t)j * HH);
            for (int i4 = g; i4 < 128; i4 += 4) {
                float4 w = Wv4[i4];
                #pragma unroll
                for (int b = 0; b < 8; ++b) {
                    float4 xv = x04[b * 128 + i4];
                    acc[b] = fmaf(w.x, xv.x, acc[b]);
                    acc[b] = fmaf(w.y, xv.y, acc[b]);
                    acc[b] = fmaf(w.z, xv.z, acc[b]);
                    acc[b] = fmaf(w.w, xv.w, acc[b]);
                }
            }
            #pragma unroll
            for (int d = 2; d; d >>= 1) {
                #pragma unroll
                for (int b = 0; b < 8; ++b) acc[b] += __shfl_xor(acc[b], d);
            }
            if (g == 0) {
                float bv = ai_b[l * 3 * HH + 2 * HH + j];
                #pragma unroll
                for (int b = 0; b < 8; ++b) sS[b * 64 + jj] = acc[b] + bv;
            }
        }
        __syncthreads();
        // opart: vpart[bid][b][j] = sum_m sV[b][m] * Wo[j, bid*64+m]
        for (int rep = 0; rep < 2; ++rep) {
            int oj = tid + rep * 256;
            const float4* wo4 = reinterpret_cast<const float4*>(
                ao_w + (size_t)l * HH * HH + (size_t)oj * HH + bid * 64);
            float ap[8] = {0,0,0,0,0,0,0,0};
            #pragma unroll
            for (int m4 = 0; m4 < 16; ++m4) {
                float4 w = wo4[m4];
                #pragma unroll
                for (int b = 0; b < 8; ++b) {
                    ap[b] += w.x * sS[b * 64 + m4 * 4]
                           + w.y * sS[b * 64 + m4 * 4 + 1]
                           + w.z * sS[b * 64 + m4 * 4 + 2]
                           + w.w * sS[b * 64 + m4 * 4 + 3];
                }
            }
            #pragma unroll
            for (int b = 0; b < 8; ++b)
                vpart[(size_t)bid * 4096 + b * 512 + oj] = ap[b];
        }
        if (bid == 0) {
            for (int idx = tid; idx < 4096; idx += 256)
                t1base[idx] = x0[idx] + ao_b[l * HH + (idx & 511)];
        }
    } else if (mode == 1) {
        // ---------------- FF: T' = x1 + silu(x1@W1)@W2 ---------------------
        // reconstruct t1
        for (int idx = tid; idx < 4096; idx += 256) {
            float v = t1base[idx];
            #pragma unroll
            for (int q = 0; q < 8; ++q) v += vpart[q * 4096 + idx];
            sT[idx] = v;
        }
        __syncthreads();
        ln8(sT, sX, HH, 9, ln1w + l * HH, ln1b + l * HH, s_m, s_r, tid);
        // f slice: 128 outputs, G=2, silu
        {
            int jj = tid >> 1, g = tid & 1;
            int j = bid * 128 + jj;
            float acc[8] = {0,0,0,0,0,0,0,0};
            const float4* W14 = reinterpret_cast<const float4*>(
                f1_w + (size_t)l * 4 * HH * HH + (size_t)j * HH);
            for (int i4 = g; i4 < 128; i4 += 2) {
                float4 w = W14[i4];
                #pragma unroll
                for (int b = 0; b < 8; ++b) {
                    float4 xv = sX4[b * 128 + i4];
                    acc[b] = fmaf(w.x, xv.x, acc[b]);
                    acc[b] = fmaf(w.y, xv.y, acc[b]);
                    acc[b] = fmaf(w.z, xv.z, acc[b]);
                    acc[b] = fmaf(w.w, xv.w, acc[b]);
                }
            }
            #pragma unroll
            for (int b = 0; b < 8; ++b) acc[b] += __shfl_xor(acc[b], 1);
            if (g == 0) {
                float bf = f1_b[l * 4 * HH + j];
                #pragma unroll
                for (int b = 0; b < 8; ++b) {
                    float v = acc[b] + bf;
                    v = v / (1.f + expf(-v));
                    sS[b * 128 + jj] = v;
                }
            }
        }
        __syncthreads();
        // fpart: fpart[bid][b][j] = sum_m sF[b][m] * W2[j, bid*128+m]
        for (int rep = 0; rep < 2; ++rep) {
            int oj = tid + rep * 256;
            const float4* w24 = reinterpret_cast<const float4*>(
                f2_w + (size_t)l * HH * 4 * HH + (size_t)oj * 4 * HH + bid * 128);
            float ap[8] = {0,0,0,0,0,0,0,0};
            #pragma unroll
            for (int m4 = 0; m4 < 32; ++m4) {
                float4 w = w24[m4];
                #pragma unroll
                for (int b = 0; b < 8; ++b) {
                    ap[b] += w.x * sS[b * 128 + m4 * 4]
                           + w.y * sS[b * 128 + m4 * 4 + 1]
                           + w.z * sS[b * 128 + m4 * 4 + 2]
                           + w.w * sS[b * 128 + m4 * 4 + 3];
                }
            }
            #pragma unroll
            for (int b = 0; b < 8; ++b)
                fpart[(size_t)bid * 4096 + b * 512 + oj] = ap[b];
        }
        if (bid == 0) {
            for (int idx = tid; idx < 4096; idx += 256)
                Tbase[idx] = sX[idx] + f2_b[l * HH + (idx & 511)];
        }
    } else {
        // ---------------- tail: p1 + LN + preds (single block) -------------
        for (int idx = tid; idx < 4096; idx += 256) {
            float v = Tbase[idx];
            #pragma unroll 4
            for (int q = 0; q < 16; ++q) v += fpart[q * 4096 + idx];
            sT[idx] = v;
        }
        __syncthreads();
        ln8(sT, sX, HH, 9, ln2w + 2 * HH, ln2b + 2 * HH, s_m, s_r, tid);
        ln8(sX, sX, HH, 9, nAw, nAb, s_m, s_r, tid);
        // p = silu(xA @ p1^T + p1b): 256 outputs, one per thread
        {
            int j = tid;
            float acc[8] = {0,0,0,0,0,0,0,0};
            const float4* W4 = reinterpret_cast<const float4*>(p1w + (size_t)j * HH);
            for (int i4 = 0; i4 < 128; ++i4) {
                float4 w = W4[i4];
                #pragma unroll
                for (int b = 0; b < 8; ++b) {
                    float4 xv = sX4[b * 128 + i4];
                    acc[b] = fmaf(w.x, xv.x, acc[b]);
                    acc[b] = fmaf(w.y, xv.y, acc[b]);
                    acc[b] = fmaf(w.z, xv.z, acc[b]);
                    acc[b] = fmaf(w.w, xv.w, acc[b]);
                }
            }
            float bp = p1b[j];
            #pragma unroll
            for (int b = 0; b < 8; ++b) {
                float v = acc[b] + bp;
                v = v / (1.f + expf(-v));
                sS[b * 256 + j] = v;
            }
        }
        __syncthreads();
        ln8(sS, sS, 256, 8, nBw, nBb, s_m, s_r, tid);
        {
            int b = tid >> 5, k = tid & 31;
            float s = 0.f;
            for (int kk = k; kk < 256; kk += 32) s += sS[b * 256 + kk] * p2w[kk];
            #pragma unroll
            for (int d = 16; d; d >>= 1) s += __shfl_down(s, d);
            if (k == 0) preds[b] = s + p2b[0];
        }
    }
}

// ---------------------------------------------------------------------------
extern "C" void kernel_launch(void* const* d_in, const int* in_sizes, int n_in,
                              void* d_out, int out_size, void* d_ws, size_t ws_size,
                              hipStream_t stream)
{
    const float* x      = (const float*)d_in[0];
    const float* proj_w = (const float*)d_in[1];
    const float* proj_b = (const float*)d_in[2];
    const float* pe     = (const float*)d_in[3];
    const float* hebb   = (const float*)d_in[4];
    const float* ai_w   = (const float*)d_in[5];
    const float* ai_b   = (const float*)d_in[6];
    const float* ao_w   = (const float*)d_in[7];
    const float* ao_b   = (const float*)d_in[8];
    const float* f1_w   = (const float*)d_in[9];
    const float* f1_b   = (const float*)d_in[10];
    const float* f2_w   = (const float*)d_in[11];
    const float* f2_b   = (const float*)d_in[12];
    const float* ln1w   = (const float*)d_in[13];
    const float* ln1b   = (const float*)d_in[14];
    const float* ln2w   = (const float*)d_in[15];
    const float* ln2b   = (const float*)d_in[16];
    const float* nAw    = (const float*)d_in[17];
    const float* nAb    = (const float*)d_in[18];
    const float* nBw    = (const float*)d_in[19];
    const float* nBb    = (const float*)d_in[20];
    const float* p1w    = (const float*)d_in[21];
    const float* p1b    = (const float*)d_in[22];
    const float* p2w    = (const float*)d_in[23];
    const float* p2b    = (const float*)d_in[24];

    float* out   = (float*)d_out;
    // output layout: preds(8) | A(B*S*S) | mask(B*S*S) | psi(B*S*2)
    float* preds = out;
    float* A     = out + 8;
    float* Mask  = out + 8 + (size_t)BB * SS * SS;
    float* Psi   = out + 8 + (size_t)2 * BB * SS * SS;

    float* ws     = (float*)d_ws;
    float* Tbase  = ws;               // 4096
    float* t1base = ws + 4096;        // 4096
    float* vpart  = ws + 8192;        // 8 x 4096
    float* fpart  = ws + 40960;       // 16 x 4096

    // ---- Launch 1: psi + h0 ----
    psiM_kernel<<<NROWS / 16, 256, 0, stream>>>(x, proj_w, proj_b, pe, hebb, Psi, Tbase);

    // ---- 7 carriers, stores moonlighted ----
    int arow = 0;
    auto q_of = [&](int i) { return (i < 6) ? 2341 : (NROWS - 2341 * 6); };

    int ci = 0;
    for (int l = 0; l < LL; ++l) {
        int q;
        q = q_of(ci++);
        carrier<<<8 + q, 256, 0, stream>>>(
            0, l, 8, arow, Psi,
            ai_w, ai_b, ao_w, ao_b, f1_w, f1_b, f2_w, f2_b,
            ln1w, ln1b, ln2w, ln2b, nAw, nAb, nBw, nBb, p1w, p1b, p2w, p2b,
            Tbase, t1base, vpart, fpart, preds, A, Mask);
        arow += q;
        q = q_of(ci++);
        carrier<<<16 + q, 256, 0, stream>>>(
            1, l, 16, arow, Psi,
            ai_w, ai_b, ao_w, ao_b, f1_w, f1_b, f2_w, f2_b,
            ln1w, ln1b, ln2w, ln2b, nAw, nAb, nBw, nBb, p1w, p1b, p2w, p2b,
            Tbase, t1base, vpart, fpart, preds, A, Mask);
        arow += q;
    }
    {
        int q = q_of(ci++);
        carrier<<<1 + q, 256, 0, stream>>>(
            2, 0, 1, arow, Psi,
            ai_w, ai_b, ao_w, ao_b, f1_w, f1_b, f2_w, f2_b,
            ln1w, ln1b, ln2w, ln2b, nAw, nAb, nBw, nBb, p1w, p1b, p2w, p2b,
            Tbase, t1base, vpart, fpart, preds, A, Mask);
        arow += q;
    }
}

// Round 14
// 292.558 us; speedup vs baseline: 2.7850x; 1.0718x over previous
//
#include <hip/hip_runtime.h>
#include <hip/hip_bf16.h>

// Problem constants
#define BB 8
#define SS 2048
#define DD 256
#define HH 512
#define LL 3
#define NROWS (BB * SS)
#define PSIB 1024        // psi blocks in launch 2
#define WCBN 192         // Wc blocks in launch 2 (3 layers x 64)

typedef float floatx4 __attribute__((ext_vector_type(4)));

// ---------------------------------------------------------------------------
// A/mask row worker (NT stores; verified R10)
// ---------------------------------------------------------------------------
__device__ __forceinline__ void amask_row(const float* __restrict__ psi,
                                          float* __restrict__ A, float* __restrict__ M,
                                          int blk)
{
    int tid = threadIdx.x;
    int b = blk >> 11, i = blk & (SS - 1);
    float2 pi = *reinterpret_cast<const float2*>(psi + (size_t)blk * 2);
    #pragma unroll
    for (int c = 0; c < 2; ++c) {
        int j0 = c * 1024 + tid * 4;
        const float4* pr = reinterpret_cast<const float4*>(psi + ((size_t)b * SS + j0) * 2);
        float4 q0 = pr[0], q1 = pr[1];
        floatx4 o;
        o.x = pi.x * q0.x + pi.y * q0.y;
        o.y = pi.x * q0.z + pi.y * q0.w;
        o.z = pi.x * q1.x + pi.y * q1.y;
        o.w = pi.x * q1.z + pi.y * q1.w;
        size_t rb = (size_t)blk * SS + j0;
        __builtin_nontemporal_store(o, reinterpret_cast<floatx4*>(A + rb));
        floatx4 m;
        m.x = (i == j0    ) ? 1.f : 0.f;
        m.y = (i == j0 + 1) ? 1.f : 0.f;
        m.z = (i == j0 + 2) ? 1.f : 0.f;
        m.w = (i == j0 + 3) ? 1.f : 0.f;
        __builtin_nontemporal_store(m, reinterpret_cast<floatx4*>(M + rb));
    }
}

// ---------------------------------------------------------------------------
// Launch 1: M[k][t] = sum_d pw[d][k]*pe[d][t]; c = pb . pe (verified R10)
// ---------------------------------------------------------------------------
__global__ void compute_M(const float* __restrict__ pw, const float* __restrict__ pb,
                          const float* __restrict__ pe, float* __restrict__ Mc)
{
    __shared__ float s0[4][256], s1[4][256];
    int tid = threadIdx.x;
    int k = tid & 255;
    int sub = tid >> 8;
    float a0 = 0.f, a1 = 0.f;
    #pragma unroll 8
    for (int d = sub * 64; d < sub * 64 + 64; ++d) {
        float w = pw[d * DD + k];
        a0 += w * pe[2 * d];
        a1 += w * pe[2 * d + 1];
    }
    s0[sub][k] = a0;
    s1[sub][k] = a1;
    __syncthreads();
    if (tid < 256) {
        Mc[2 * tid]     = s0[0][tid] + s0[1][tid] + s0[2][tid] + s0[3][tid];
        Mc[2 * tid + 1] = s1[0][tid] + s1[1][tid] + s1[2][tid] + s1[3][tid];
    }
    if (tid < 64) {
        float c0 = 0.f, c1 = 0.f;
        for (int d = tid; d < DD; d += 64) {
            c0 += pb[d] * pe[2 * d];
            c1 += pb[d] * pe[2 * d + 1];
        }
        #pragma unroll
        for (int dd = 32; dd; dd >>= 1) {
            c0 += __shfl_xor(c0, dd);
            c1 += __shfl_xor(c1, dd);
        }
        if (tid == 0) { Mc[512] = c0; Mc[513] = c1; }
    }
}

// ---------------------------------------------------------------------------
// Launch 2: blocks 0..1023  : psi (16 rows each, from Mc) + h0 -> T
//           blocks 1024..   : Wc = Wo@Wv, bc = Wo@bv + bo (8x-unrolled m-loop)
// ---------------------------------------------------------------------------
__global__ void psi_wc_kernel(const float* __restrict__ x, const float* __restrict__ Mc,
                              const float* __restrict__ hebb,
                              const float* __restrict__ ai_w, const float* __restrict__ ai_b,
                              const float* __restrict__ ao_w, const float* __restrict__ ao_b,
                              float* __restrict__ psi, float* __restrict__ T,
                              float* __restrict__ Wc, float* __restrict__ bc)
{
    __shared__ __align__(16) float sW[8 * HH];   // 16 KB (Wc staging)
    const int tid = threadIdx.x;
    const int bid = blockIdx.x;

    if (bid >= PSIB) {
        // ---- Wc blocks ----
        int wcb = bid - PSIB;
        int l = wcb >> 6;                 // 0..2
        int j0 = (wcb & 63) * 8;          // 8 Wo rows
        const float* WoB = ao_w + (size_t)l * HH * HH;
        for (int idx = tid; idx < 8 * HH; idx += 256) {
            int r = idx >> 9, m = idx & 511;
            sW[idx] = WoB[(size_t)(j0 + r) * HH + m];
        }
        __syncthreads();
        const float* WvB = ai_w + ((size_t)l * 3 * HH + 2 * HH) * HH;
        int k0 = tid, k1 = tid + 256;
        float acc0[8] = {0,0,0,0,0,0,0,0};
        float acc1[8] = {0,0,0,0,0,0,0,0};
        for (int m = 0; m < HH; m += 8) {
            float av[8], bv8[8];
            #pragma unroll
            for (int u = 0; u < 8; ++u) {
                av[u]  = WvB[(size_t)(m + u) * HH + k0];
                bv8[u] = WvB[(size_t)(m + u) * HH + k1];
            }
            #pragma unroll
            for (int u = 0; u < 8; ++u) {
                #pragma unroll
                for (int r = 0; r < 8; ++r) {
                    float wo = sW[r * HH + m + u];
                    acc0[r] = fmaf(wo, av[u], acc0[r]);
                    acc1[r] = fmaf(wo, bv8[u], acc1[r]);
                }
            }
        }
        #pragma unroll
        for (int r = 0; r < 8; ++r) {
            Wc[((size_t)l * HH + j0 + r) * HH + k0] = acc0[r];
            Wc[((size_t)l * HH + j0 + r) * HH + k1] = acc1[r];
        }
        // bc[j0+r] = ao_b + Wo[j0+r,:] . bv   (8 rows x 32 lanes)
        {
            int r = tid >> 5, lane = tid & 31;
            const float* bvB = ai_b + l * 3 * HH + 2 * HH;
            float s = 0.f;
            for (int m = lane; m < HH; m += 32) s += sW[r * HH + m] * bvB[m];
            #pragma unroll
            for (int d = 16; d; d >>= 1) s += __shfl_down(s, d);
            if (lane == 0) bc[l * HH + j0 + r] = ao_b[l * HH + j0 + r] + s;
        }
        return;
    }

    // ---- psi blocks (R10-verified) + h0 (R11-verified) ----
    int wave = tid >> 6, lane = tid & 63;
    const float4* Mc4 = reinterpret_cast<const float4*>(Mc);
    float4 mA = Mc4[lane * 2];
    float4 mB = Mc4[lane * 2 + 1];
    float c0 = Mc[512], c1 = Mc[513];
    int base = bid * 16 + wave * 4;
    #pragma unroll
    for (int it = 0; it < 4; ++it) {
        int rid = base + it;
        float4 v = *reinterpret_cast<const float4*>(x + (size_t)rid * DD + lane * 4);
        float a0 = v.x * mA.x + v.y * mA.z + v.z * mB.x + v.w * mB.z;
        float a1 = v.x * mA.y + v.y * mA.w + v.z * mB.y + v.w * mB.w;
        #pragma unroll
        for (int d = 32; d; d >>= 1) {
            a0 += __shfl_xor(a0, d);
            a1 += __shfl_xor(a1, d);
        }
        a0 += c0;
        a1 += c1;
        float n = sqrtf(a0 * a0 + a1 * a1);
        float scale = 1.f / (n + 1e-8f);
        float r = n * scale;
        #pragma unroll
        for (int i7 = 0; i7 < 7; ++i7) {
            float f = r / (r + 1e-8f);
            scale *= f;
            r *= f;
        }
        float px = a0 * scale, py = a1 * scale;
        if (lane == 0) {
            float2 pv;
            pv.x = px;
            pv.y = py;
            *reinterpret_cast<float2*>(psi + (size_t)rid * 2) = pv;
        }
        if ((rid & (SS - 1)) == SS - 1) {       // h0 -> T
            int b = rid >> 11;
            for (int j = lane; j < HH; j += 64)
                T[(size_t)b * HH + j] = px * hebb[2 * j] + py * hebb[2 * j + 1];
        }
    }
}

// ---------------------------------------------------------------------------
// Generic tiny-batch GEMM carrier (verified R10/R11), + moonlighted stores.
// ---------------------------------------------------------------------------
__global__ void head_mm(const float* __restrict__ X, int K,
                        const float* __restrict__ xlnw, const float* __restrict__ xlnb,
                        const float* __restrict__ W, const float* __restrict__ bias,
                        const float* __restrict__ res,
                        const float* __restrict__ reslnw, const float* __restrict__ reslnb,
                        float* __restrict__ out, int J, int G, int act,
                        const float* __restrict__ psi,
                        float* __restrict__ Ao, float* __restrict__ Mo,
                        int mmBlocks, int arow0)
{
    const int bid = blockIdx.x;
    if (bid >= mmBlocks) {
        int r = arow0 + (bid - mmBlocks);
        if (r < NROWS) amask_row(psi, Ao, Mo, r);
        return;
    }

    extern __shared__ float sX[];           // 8*K floats when LN is active
    __shared__ float s_m[8], s_r[8], s_rm[8], s_rr[8];
    const int tid = threadIdx.x;
    const int row = tid >> 5, lane = tid & 31;
    const bool doLN = (xlnw != nullptr);
    const bool doRLN = (res != nullptr) && (reslnw != nullptr);

    if (doLN) {
        float s = 0.f, ss = 0.f;
        for (int k = lane; k < K; k += 32) {
            float v = X[row * K + k];
            s += v; ss += v * v;
        }
        for (int d = 16; d; d >>= 1) { s += __shfl_down(s, d); ss += __shfl_down(ss, d); }
        if (lane == 0) {
            float m = s / K;
            s_m[row] = m;
            s_r[row] = rsqrtf(ss / K - m * m + 1e-5f);
        }
    }
    if (doRLN) {
        float s = 0.f, ss = 0.f;
        for (int k = lane; k < J; k += 32) {
            float v = res[row * J + k];
            s += v; ss += v * v;
        }
        for (int d = 16; d; d >>= 1) { s += __shfl_down(s, d); ss += __shfl_down(ss, d); }
        if (lane == 0) {
            float m = s / J;
            s_rm[row] = m;
            s_rr[row] = rsqrtf(ss / J - m * m + 1e-5f);
        }
    }
    __syncthreads();

    if (doLN) {
        for (int idx = tid; idx < 8 * K; idx += 256) {
            int b = idx / K, k = idx - b * K;
            sX[idx] = (X[idx] - s_m[b]) * s_r[b] * xlnw[k] + xlnb[k];
        }
        __syncthreads();
    }

    const float* __restrict__ Xp = doLN ? (const float*)sX : X;
    const int g = tid & (G - 1);
    const int jj = tid / G;
    const int j = bid * (256 / G) + jj;

    float acc[8] = {0.f, 0.f, 0.f, 0.f, 0.f, 0.f, 0.f, 0.f};
    if (j < J) {
        const float4* W4 = reinterpret_cast<const float4*>(W + (size_t)j * K);
        const int K4 = K >> 2;
        for (int i4 = g; i4 < K4; i4 += G) {
            float4 w4 = W4[i4];
            int k = i4 << 2;
            #pragma unroll
            for (int b = 0; b < 8; ++b) {
                float4 xv = *reinterpret_cast<const float4*>(Xp + b * K + k);
                acc[b] = fmaf(w4.x, xv.x, acc[b]);
                acc[b] = fmaf(w4.y, xv.y, acc[b]);
                acc[b] = fmaf(w4.z, xv.z, acc[b]);
                acc[b] = fmaf(w4.w, xv.w, acc[b]);
            }
        }
    }
    for (int d = G >> 1; d; d >>= 1) {
        #pragma unroll
        for (int b = 0; b < 8; ++b) acc[b] += __shfl_down(acc[b], d);
    }
    if (g == 0 && j < J) {
        float bs = bias ? bias[j] : 0.f;
        #pragma unroll
        for (int b = 0; b < 8; ++b) {
            float v = acc[b] + bs;
            if (act) v = v / (1.f + expf(-v));   // silu
            if (res) {
                float rv = res[(size_t)b * J + j];
                if (reslnw) rv = (rv - s_rm[b]) * s_rr[b] * reslnw[j] + reslnb[j];
                v += rv;
            }
            out[(size_t)b * J + j] = v;
        }
    }
}

// ---------------------------------------------------------------------------
// Per-row LN for [8][N] in LDS (verified R13). sh = log2(N). In-place safe.
// ---------------------------------------------------------------------------
__device__ __forceinline__ void ln8(const float* in, float* out, int N, int sh,
                                    const float* __restrict__ w,
                                    const float* __restrict__ bvec,
                                    float* s_m, float* s_r, int tid)
{
    int row = tid >> 5, lane = tid & 31;
    float s = 0.f, ss = 0.f;
    for (int k = lane; k < N; k += 32) {
        float v = in[(row << sh) + k];
        s += v; ss += v * v;
    }
    #pragma unroll
    for (int d = 16; d; d >>= 1) { s += __shfl_down(s, d); ss += __shfl_down(ss, d); }
    if (lane == 0) {
        float m = s / N;
        s_m[row] = m;
        s_r[row] = rsqrtf(ss / N - m * m + 1e-5f);
    }
    __syncthreads();
    for (int idx = tid; idx < (N << 3); idx += 256) {
        int b = idx >> sh, k = idx & (N - 1);
        out[idx] = (in[idx] - s_m[b]) * s_r[b] * w[k] + bvec[k];
    }
    __syncthreads();
}

// ---------------------------------------------------------------------------
// Tail carrier: block 0 = LN(ln2[2])->LN(normA)->p1/silu->LN(normB)->preds
// (verified R13 tail). Blocks >=1 stream A/mask rows.
// ---------------------------------------------------------------------------
__global__ void tail_kernel(const float* __restrict__ T,
                            const float* __restrict__ ln2w, const float* __restrict__ ln2b,
                            const float* __restrict__ nAw, const float* __restrict__ nAb,
                            const float* __restrict__ nBw, const float* __restrict__ nBb,
                            const float* __restrict__ p1w, const float* __restrict__ p1b,
                            const float* __restrict__ p2w, const float* __restrict__ p2b,
                            float* __restrict__ preds,
                            const float* __restrict__ psi,
                            float* __restrict__ Ao, float* __restrict__ Mo, int arow0)
{
    const int bid = blockIdx.x;
    const int tid = threadIdx.x;
    if (bid >= 1) {
        int r = arow0 + (bid - 1);
        if (r < NROWS) amask_row(psi, Ao, Mo, r);
        return;
    }
    __shared__ __align__(16) float sT[8 * HH];
    __shared__ __align__(16) float sX[8 * HH];
    __shared__ __align__(16) float sS[8 * 256];
    __shared__ float s_m[8], s_r[8];
    const float4* sX4 = reinterpret_cast<const float4*>(sX);

    for (int idx = tid; idx < 4096; idx += 256) sT[idx] = T[idx];
    __syncthreads();
    ln8(sT, sX, HH, 9, ln2w + 2 * HH, ln2b + 2 * HH, s_m, s_r, tid);
    ln8(sX, sX, HH, 9, nAw, nAb, s_m, s_r, tid);
    {
        int j = tid;
        float acc[8] = {0,0,0,0,0,0,0,0};
        const float4* W4 = reinterpret_cast<const float4*>(p1w + (size_t)j * HH);
        for (int i4 = 0; i4 < 128; ++i4) {
            float4 w = W4[i4];
            #pragma unroll
            for (int b = 0; b < 8; ++b) {
                float4 xv = sX4[b * 128 + i4];
                acc[b] = fmaf(w.x, xv.x, acc[b]);
                acc[b] = fmaf(w.y, xv.y, acc[b]);
                acc[b] = fmaf(w.z, xv.z, acc[b]);
                acc[b] = fmaf(w.w, xv.w, acc[b]);
            }
        }
        float bp = p1b[j];
        #pragma unroll
        for (int b = 0; b < 8; ++b) {
            float v = acc[b] + bp;
            v = v / (1.f + expf(-v));
            sS[b * 256 + j] = v;
        }
    }
    __syncthreads();
    ln8(sS, sS, 256, 8, nBw, nBb, s_m, s_r, tid);
    {
        int b = tid >> 5, k = tid & 31;
        float s = 0.f;
        for (int kk = k; kk < 256; kk += 32) s += sS[b * 256 + kk] * p2w[kk];
        #pragma unroll
        for (int d = 16; d; d >>= 1) s += __shfl_down(s, d);
        if (k == 0) preds[b] = s + p2b[0];
    }
}

// ---------------------------------------------------------------------------
extern "C" void kernel_launch(void* const* d_in, const int* in_sizes, int n_in,
                              void* d_out, int out_size, void* d_ws, size_t ws_size,
                              hipStream_t stream)
{
    const float* x      = (const float*)d_in[0];
    const float* proj_w = (const float*)d_in[1];
    const float* proj_b = (const float*)d_in[2];
    const float* pe     = (const float*)d_in[3];
    const float* hebb   = (const float*)d_in[4];
    const float* ai_w   = (const float*)d_in[5];
    const float* ai_b   = (const float*)d_in[6];
    const float* ao_w   = (const float*)d_in[7];
    const float* ao_b   = (const float*)d_in[8];
    const float* f1_w   = (const float*)d_in[9];
    const float* f1_b   = (const float*)d_in[10];
    const float* f2_w   = (const float*)d_in[11];
    const float* f2_b   = (const float*)d_in[12];
    const float* ln1w   = (const float*)d_in[13];
    const float* ln1b   = (const float*)d_in[14];
    const float* ln2w   = (const float*)d_in[15];
    const float* ln2b   = (const float*)d_in[16];
    const float* nAw    = (const float*)d_in[17];
    const float* nAb    = (const float*)d_in[18];
    const float* nBw    = (const float*)d_in[19];
    const float* nBb    = (const float*)d_in[20];
    const float* p1w    = (const float*)d_in[21];
    const float* p1b    = (const float*)d_in[22];
    const float* p2w    = (const float*)d_in[23];
    const float* p2b    = (const float*)d_in[24];

    float* out   = (float*)d_out;
    // output layout: preds(8) | A(B*S*S) | mask(B*S*S) | psi(B*S*2)
    float* preds = out;
    float* A     = out + 8;
    float* Mask  = out + 8 + (size_t)BB * SS * SS;
    float* Psi   = out + 8 + (size_t)2 * BB * SS * SS;

    // Wc parked in A rows 15000+ (last Wc read = carrier 7; first overwrite =
    // tail carrier's store rows 14751+... rows >= 15000 written by tail only,
    // which runs after all Wc reads — stream-ordered safe).
    float* Wc = A + (size_t)15000 * SS;
    float* bc = Wc + 3 * HH * HH;

    float* ws = (float*)d_ws;
    float* Mc = ws;            // 514
    float* T  = ws + 640;      // 8x512
    float* T1 = ws + 8832;     // 8x512
    float* F  = ws + 12928;    // 8x2048

    // ---- Launch 1: Mc ----
    compute_M<<<1, 1024, 0, stream>>>(proj_w, proj_b, pe, Mc);
    // ---- Launch 2: psi + h0 + Wc/bc ----
    psi_wc_kernel<<<PSIB + WCBN, 256, 0, stream>>>(
        x, Mc, hebb, ai_w, ai_b, ao_w, ao_b, Psi, T, Wc, bc);

    // ---- 10 carriers: 9 layer stages + tail; stores moonlighted ----
    int arow = 0;
    const int QROW = 1639;     // 9 x 1639 = 14751; tail covers the rest
    for (int l = 0; l < LL; ++l) {
        const float* pxw = l ? ln2w + (l - 1) * HH : nullptr;
        const float* pxb = l ? ln2b + (l - 1) * HH : nullptr;
        // t1 = resLN?(T) + (LN?(T) @ Wc^T + bc)   (J=512, K=512, G=32)
        head_mm<<<64 + QROW, 256, (pxw ? 8 * HH * 4 : 0), stream>>>(
            T, HH, pxw, pxb,
            Wc + (size_t)l * HH * HH, bc + l * HH,
            T, pxw, pxb, T1, HH, 32, 0,
            Psi, A, Mask, 64, arow);
        arow += QROW;
        // f = silu(LN(t1,ln1) @ W1^T + b1)        (J=2048, K=512, G=16)
        head_mm<<<128 + QROW, 256, 8 * HH * 4, stream>>>(
            T1, HH, ln1w + l * HH, ln1b + l * HH,
            f1_w + (size_t)l * 4 * HH * HH, f1_b + l * 4 * HH,
            nullptr, nullptr, nullptr, F, 4 * HH, 16, 1,
            Psi, A, Mask, 128, arow);
        arow += QROW;
        // t2 = LN(t1,ln1) + (f @ W2^T + b2)       (J=512, K=2048, G=64)
        head_mm<<<128 + QROW, 256, 0, stream>>>(
            F, 4 * HH, nullptr, nullptr,
            f2_w + (size_t)l * HH * 4 * HH, f2_b + l * HH,
            T1, ln1w + l * HH, ln1b + l * HH, T, HH, 64, 0,
            Psi, A, Mask, 128, arow);
        arow += QROW;
    }
    // ---- tail: LN chain + p1 + preds (block 0) + remaining store rows ----
    {
        int qrem = NROWS - arow;   // 1633
        tail_kernel<<<1 + qrem, 256, 0, stream>>>(
            T, ln2w, ln2b, nAw, nAb, nBw, nBb, p1w, p1b, p2w, p2b,
            preds, Psi, A, Mask, arow);
    }
}

// Round 15
// 206.563 us; speedup vs baseline: 3.9444x; 1.4163x over previous
//
#include <hip/hip_runtime.h>
#include <hip/hip_bf16.h>

// Problem constants
#define BB 8
#define SS 2048
#define DD 256
#define HH 512
#define LL 3
#define NROWS (BB * SS)

typedef float floatx4 __attribute__((ext_vector_type(4)));

// ---------------------------------------------------------------------------
// A/mask row worker (NT stores; verified R10)
// ---------------------------------------------------------------------------
__device__ __forceinline__ void amask_row(const float* __restrict__ psi,
                                          float* __restrict__ A, float* __restrict__ M,
                                          int blk)
{
    int tid = threadIdx.x;
    int b = blk >> 11, i = blk & (SS - 1);
    float2 pi = *reinterpret_cast<const float2*>(psi + (size_t)blk * 2);
    #pragma unroll
    for (int c = 0; c < 2; ++c) {
        int j0 = c * 1024 + tid * 4;
        const float4* pr = reinterpret_cast<const float4*>(psi + ((size_t)b * SS + j0) * 2);
        float4 q0 = pr[0], q1 = pr[1];
        floatx4 o;
        o.x = pi.x * q0.x + pi.y * q0.y;
        o.y = pi.x * q0.z + pi.y * q0.w;
        o.z = pi.x * q1.x + pi.y * q1.y;
        o.w = pi.x * q1.z + pi.y * q1.w;
        size_t rb = (size_t)blk * SS + j0;
        __builtin_nontemporal_store(o, reinterpret_cast<floatx4*>(A + rb));
        floatx4 m;
        m.x = (i == j0    ) ? 1.f : 0.f;
        m.y = (i == j0 + 1) ? 1.f : 0.f;
        m.z = (i == j0 + 2) ? 1.f : 0.f;
        m.w = (i == j0 + 3) ? 1.f : 0.f;
        __builtin_nontemporal_store(m, reinterpret_cast<floatx4*>(M + rb));
    }
}

// ---------------------------------------------------------------------------
// Launch 1: M[k][t] = sum_d pw[d][k]*pe[d][t]; c = pb . pe (verified R10)
// ---------------------------------------------------------------------------
__global__ void compute_M(const float* __restrict__ pw, const float* __restrict__ pb,
                          const float* __restrict__ pe, float* __restrict__ Mc)
{
    __shared__ float s0[4][256], s1[4][256];
    int tid = threadIdx.x;
    int k = tid & 255;
    int sub = tid >> 8;
    float a0 = 0.f, a1 = 0.f;
    #pragma unroll 8
    for (int d = sub * 64; d < sub * 64 + 64; ++d) {
        float w = pw[d * DD + k];
        a0 += w * pe[2 * d];
        a1 += w * pe[2 * d + 1];
    }
    s0[sub][k] = a0;
    s1[sub][k] = a1;
    __syncthreads();
    if (tid < 256) {
        Mc[2 * tid]     = s0[0][tid] + s0[1][tid] + s0[2][tid] + s0[3][tid];
        Mc[2 * tid + 1] = s1[0][tid] + s1[1][tid] + s1[2][tid] + s1[3][tid];
    }
    if (tid < 64) {
        float c0 = 0.f, c1 = 0.f;
        for (int d = tid; d < DD; d += 64) {
            c0 += pb[d] * pe[2 * d];
            c1 += pb[d] * pe[2 * d + 1];
        }
        #pragma unroll
        for (int dd = 32; dd; dd >>= 1) {
            c0 += __shfl_xor(c0, dd);
            c1 += __shfl_xor(c1, dd);
        }
        if (tid == 0) { Mc[512] = c0; Mc[513] = c1; }
    }
}

// ---------------------------------------------------------------------------
// Launch 2: psi (R2-verified 4-lane-group structure: 16 float4 loads in
// flight per group) + fused h0 (LDS broadcast in the 8 owner blocks).
// 256 blocks x 256 threads; 64 rows/block.
// ---------------------------------------------------------------------------
__global__ void psi_kernel(const float* __restrict__ x, const float* __restrict__ Mc,
                           const float* __restrict__ hebb,
                           float* __restrict__ psi, float* __restrict__ T)
{
    __shared__ float sM[516];
    __shared__ float sH[2];
    int tid = threadIdx.x;
    for (int i = tid; i < 514; i += 256) sM[i] = Mc[i];
    __syncthreads();

    int sub = tid & 3;
    int rloc = tid >> 2;                    // 0..63
    int rid = blockIdx.x * 64 + rloc;
    const float4* xr = reinterpret_cast<const float4*>(x + (size_t)rid * DD);
    float a0 = 0.f, a1 = 0.f;
    #pragma unroll
    for (int i = sub; i < DD / 4; i += 4) {   // 16 iterations, fully unrolled
        float4 v = xr[i];
        int k2 = i * 8;
        a0 += v.x * sM[k2]     + v.y * sM[k2 + 2] + v.z * sM[k2 + 4] + v.w * sM[k2 + 6];
        a1 += v.x * sM[k2 + 1] + v.y * sM[k2 + 3] + v.z * sM[k2 + 5] + v.w * sM[k2 + 7];
    }
    a0 += __shfl_xor(a0, 1); a0 += __shfl_xor(a0, 2);
    a1 += __shfl_xor(a1, 1); a1 += __shfl_xor(a1, 2);

    bool leader = (sub == 0);
    float px = 0.f, py = 0.f;
    if (leader) {
        a0 += sM[512];   // bias added once, after reduction (R2-verified)
        a1 += sM[513];
        float n = sqrtf(a0 * a0 + a1 * a1);
        float scale = 1.f / (n + 1e-8f);
        float r = n * scale;
        #pragma unroll
        for (int it = 0; it < 7; ++it) {
            float f = r / (r + 1e-8f);
            scale *= f;
            r *= f;
        }
        px = a0 * scale;
        py = a1 * scale;
        float2 pv;
        pv.x = px;
        pv.y = py;
        *reinterpret_cast<float2*>(psi + (size_t)rid * 2) = pv;
    }

    // h0: row b*SS + (SS-1) lives in blocks with (blockIdx & 31)==31, rloc==63
    if ((blockIdx.x & 31) == 31) {          // block-uniform branch
        if (leader && rloc == 63) { sH[0] = px; sH[1] = py; }
        __syncthreads();
        float hx = sH[0], hy = sH[1];
        int b = blockIdx.x >> 5;
        T[(size_t)b * HH + tid]       = hx * hebb[2 * tid]         + hy * hebb[2 * tid + 1];
        T[(size_t)b * HH + tid + 256] = hx * hebb[2 * (tid + 256)] + hy * hebb[2 * (tid + 256) + 1];
    }
}

// ---------------------------------------------------------------------------
// Generic tiny-batch GEMM carrier (verified R10/R14), + moonlighted stores.
// ---------------------------------------------------------------------------
__global__ void head_mm(const float* __restrict__ X, int K,
                        const float* __restrict__ xlnw, const float* __restrict__ xlnb,
                        const float* __restrict__ W, const float* __restrict__ bias,
                        const float* __restrict__ res,
                        const float* __restrict__ reslnw, const float* __restrict__ reslnb,
                        float* __restrict__ out, int J, int G, int act,
                        const float* __restrict__ psi,
                        float* __restrict__ Ao, float* __restrict__ Mo,
                        int mmBlocks, int arow0)
{
    const int bid = blockIdx.x;
    if (bid >= mmBlocks) {
        int r = arow0 + (bid - mmBlocks);
        if (r < NROWS) amask_row(psi, Ao, Mo, r);
        return;
    }

    extern __shared__ float sX[];
    __shared__ float s_m[8], s_r[8], s_rm[8], s_rr[8];
    const int tid = threadIdx.x;
    const int row = tid >> 5, lane = tid & 31;
    const bool doLN = (xlnw != nullptr);
    const bool doRLN = (res != nullptr) && (reslnw != nullptr);

    if (doLN) {
        float s = 0.f, ss = 0.f;
        for (int k = lane; k < K; k += 32) {
            float v = X[row * K + k];
            s += v; ss += v * v;
        }
        for (int d = 16; d; d >>= 1) { s += __shfl_down(s, d); ss += __shfl_down(ss, d); }
        if (lane == 0) {
            float m = s / K;
            s_m[row] = m;
            s_r[row] = rsqrtf(ss / K - m * m + 1e-5f);
        }
    }
    if (doRLN) {
        float s = 0.f, ss = 0.f;
        for (int k = lane; k < J; k += 32) {
            float v = res[row * J + k];
            s += v; ss += v * v;
        }
        for (int d = 16; d; d >>= 1) { s += __shfl_down(s, d); ss += __shfl_down(ss, d); }
        if (lane == 0) {
            float m = s / J;
            s_rm[row] = m;
            s_rr[row] = rsqrtf(ss / J - m * m + 1e-5f);
        }
    }
    __syncthreads();

    if (doLN) {
        for (int idx = tid; idx < 8 * K; idx += 256) {
            int b = idx / K, k = idx - b * K;
            sX[idx] = (X[idx] - s_m[b]) * s_r[b] * xlnw[k] + xlnb[k];
        }
        __syncthreads();
    }

    const float* __restrict__ Xp = doLN ? (const float*)sX : X;
    const int g = tid & (G - 1);
    const int jj = tid / G;
    const int j = bid * (256 / G) + jj;

    float acc[8] = {0.f, 0.f, 0.f, 0.f, 0.f, 0.f, 0.f, 0.f};
    if (j < J) {
        const float4* W4 = reinterpret_cast<const float4*>(W + (size_t)j * K);
        const int K4 = K >> 2;
        for (int i4 = g; i4 < K4; i4 += G) {
            float4 w4 = W4[i4];
            int k = i4 << 2;
            #pragma unroll
            for (int b = 0; b < 8; ++b) {
                float4 xv = *reinterpret_cast<const float4*>(Xp + b * K + k);
                acc[b] = fmaf(w4.x, xv.x, acc[b]);
                acc[b] = fmaf(w4.y, xv.y, acc[b]);
                acc[b] = fmaf(w4.z, xv.z, acc[b]);
                acc[b] = fmaf(w4.w, xv.w, acc[b]);
            }
        }
    }
    for (int d = G >> 1; d; d >>= 1) {
        #pragma unroll
        for (int b = 0; b < 8; ++b) acc[b] += __shfl_down(acc[b], d);
    }
    if (g == 0 && j < J) {
        float bs = bias ? bias[j] : 0.f;
        #pragma unroll
        for (int b = 0; b < 8; ++b) {
            float v = acc[b] + bs;
            if (act) v = v / (1.f + expf(-v));   // silu
            if (res) {
                float rv = res[(size_t)b * J + j];
                if (reslnw) rv = (rv - s_rm[b]) * s_rr[b] * reslnw[j] + reslnb[j];
                v += rv;
            }
            out[(size_t)b * J + j] = v;
        }
    }
}

// ---------------------------------------------------------------------------
// Per-row LN for [8][N] in LDS (verified R13/R14). sh=log2(N). In-place safe.
// ---------------------------------------------------------------------------
__device__ __forceinline__ void ln8(const float* in, float* out, int N, int sh,
                                    const float* __restrict__ w,
                                    const float* __restrict__ bvec,
                                    float* s_m, float* s_r, int tid)
{
    int row = tid >> 5, lane = tid & 31;
    float s = 0.f, ss = 0.f;
    for (int k = lane; k < N; k += 32) {
        float v = in[(row << sh) + k];
        s += v; ss += v * v;
    }
    #pragma unroll
    for (int d = 16; d; d >>= 1) { s += __shfl_down(s, d); ss += __shfl_down(ss, d); }
    if (lane == 0) {
        float m = s / N;
        s_m[row] = m;
        s_r[row] = rsqrtf(ss / N - m * m + 1e-5f);
    }
    __syncthreads();
    for (int idx = tid; idx < (N << 3); idx += 256) {
        int b = idx >> sh, k = idx & (N - 1);
        out[idx] = (in[idx] - s_m[b]) * s_r[b] * w[k] + bvec[k];
    }
    __syncthreads();
}

// ---------------------------------------------------------------------------
// Tail carrier (verified R14): block 0 = LN chain + p1/silu + LN + preds;
// blocks >= 1 stream A/mask rows.
// ---------------------------------------------------------------------------
__global__ void tail_kernel(const float* __restrict__ T,
                            const float* __restrict__ ln2w, const float* __restrict__ ln2b,
                            const float* __restrict__ nAw, const float* __restrict__ nAb,
                            const float* __restrict__ nBw, const float* __restrict__ nBb,
                            const float* __restrict__ p1w, const float* __restrict__ p1b,
                            const float* __restrict__ p2w, const float* __restrict__ p2b,
                            float* __restrict__ preds,
                            const float* __restrict__ psi,
                            float* __restrict__ Ao, float* __restrict__ Mo, int arow0)
{
    const int bid = blockIdx.x;
    const int tid = threadIdx.x;
    if (bid >= 1) {
        int r = arow0 + (bid - 1);
        if (r < NROWS) amask_row(psi, Ao, Mo, r);
        return;
    }
    __shared__ __align__(16) float sT[8 * HH];
    __shared__ __align__(16) float sX[8 * HH];
    __shared__ __align__(16) float sS[8 * 256];
    __shared__ float s_m[8], s_r[8];
    const float4* sX4 = reinterpret_cast<const float4*>(sX);

    for (int idx = tid; idx < 4096; idx += 256) sT[idx] = T[idx];
    __syncthreads();
    ln8(sT, sX, HH, 9, ln2w + 2 * HH, ln2b + 2 * HH, s_m, s_r, tid);
    ln8(sX, sX, HH, 9, nAw, nAb, s_m, s_r, tid);
    {
        int j = tid;
        float acc[8] = {0,0,0,0,0,0,0,0};
        const float4* W4 = reinterpret_cast<const float4*>(p1w + (size_t)j * HH);
        for (int i4 = 0; i4 < 128; ++i4) {
            float4 w = W4[i4];
            #pragma unroll
            for (int b = 0; b < 8; ++b) {
                float4 xv = sX4[b * 128 + i4];
                acc[b] = fmaf(w.x, xv.x, acc[b]);
                acc[b] = fmaf(w.y, xv.y, acc[b]);
                acc[b] = fmaf(w.z, xv.z, acc[b]);
                acc[b] = fmaf(w.w, xv.w, acc[b]);
            }
        }
        float bp = p1b[j];
        #pragma unroll
        for (int b = 0; b < 8; ++b) {
            float v = acc[b] + bp;
            v = v / (1.f + expf(-v));
            sS[b * 256 + j] = v;
        }
    }
    __syncthreads();
    ln8(sS, sS, 256, 8, nBw, nBb, s_m, s_r, tid);
    {
        int b = tid >> 5, k = tid & 31;
        float s = 0.f;
        for (int kk = k; kk < 256; kk += 32) s += sS[b * 256 + kk] * p2w[kk];
        #pragma unroll
        for (int d = 16; d; d >>= 1) s += __shfl_down(s, d);
        if (k == 0) preds[b] = s + p2b[0];
    }
}

// ---------------------------------------------------------------------------
extern "C" void kernel_launch(void* const* d_in, const int* in_sizes, int n_in,
                              void* d_out, int out_size, void* d_ws, size_t ws_size,
                              hipStream_t stream)
{
    const float* x      = (const float*)d_in[0];
    const float* proj_w = (const float*)d_in[1];
    const float* proj_b = (const float*)d_in[2];
    const float* pe     = (const float*)d_in[3];
    const float* hebb   = (const float*)d_in[4];
    const float* ai_w   = (const float*)d_in[5];
    const float* ai_b   = (const float*)d_in[6];
    const float* ao_w   = (const float*)d_in[7];
    const float* ao_b   = (const float*)d_in[8];
    const float* f1_w   = (const float*)d_in[9];
    const float* f1_b   = (const float*)d_in[10];
    const float* f2_w   = (const float*)d_in[11];
    const float* f2_b   = (const float*)d_in[12];
    const float* ln1w   = (const float*)d_in[13];
    const float* ln1b   = (const float*)d_in[14];
    const float* ln2w   = (const float*)d_in[15];
    const float* ln2b   = (const float*)d_in[16];
    const float* nAw    = (const float*)d_in[17];
    const float* nAb    = (const float*)d_in[18];
    const float* nBw    = (const float*)d_in[19];
    const float* nBb    = (const float*)d_in[20];
    const float* p1w    = (const float*)d_in[21];
    const float* p1b    = (const float*)d_in[22];
    const float* p2w    = (const float*)d_in[23];
    const float* p2b    = (const float*)d_in[24];

    float* out   = (float*)d_out;
    // output layout: preds(8) | A(B*S*S) | mask(B*S*S) | psi(B*S*2)
    float* preds = out;
    float* A     = out + 8;
    float* Mask  = out + 8 + (size_t)BB * SS * SS;
    float* Psi   = out + 8 + (size_t)2 * BB * SS * SS;

    float* ws = (float*)d_ws;
    float* Mc = ws;            // 514
    float* T  = ws + 640;      // 8x512
    float* V  = ws + 4736;     // 8x512
    float* T1 = ws + 8832;     // 8x512
    float* F  = ws + 12928;    // 8x2048

    // ---- Launch 1: Mc ----
    compute_M<<<1, 1024, 0, stream>>>(proj_w, proj_b, pe, Mc);
    // ---- Launch 2: psi + h0 (4-lane-group, high load parallelism) ----
    psi_kernel<<<NROWS / 64, 256, 0, stream>>>(x, Mc, hebb, Psi, T);

    // ---- 12 layer carriers + tail; stores moonlighted ----
    int arow = 0;
    const int QROW = 1261;     // 12 x 1261 = 15132; tail covers 1252
    for (int l = 0; l < LL; ++l) {
        const float* pxw = l ? ln2w + (l - 1) * HH : nullptr;
        const float* pxb = l ? ln2b + (l - 1) * HH : nullptr;
        // v = LN?(T) @ Wv^T + bv            (J=512, K=512, G=32)
        head_mm<<<64 + QROW, 256, (pxw ? 8 * HH * 4 : 0), stream>>>(
            T, HH, pxw, pxb,
            ai_w + ((size_t)l * 3 * HH + 2 * HH) * HH, ai_b + l * 3 * HH + 2 * HH,
            nullptr, nullptr, nullptr, V, HH, 32, 0,
            Psi, A, Mask, 64, arow);
        arow += QROW;
        // t1 = resLN?(T) + (v @ Wo^T + bo)  (J=512, K=512)
        head_mm<<<64 + QROW, 256, 0, stream>>>(
            V, HH, nullptr, nullptr,
            ao_w + (size_t)l * HH * HH, ao_b + l * HH,
            T, pxw, pxb, T1, HH, 32, 0,
            Psi, A, Mask, 64, arow);
        arow += QROW;
        // f = silu(LN(t1,ln1) @ W1^T + b1)  (J=2048, K=512, G=16)
        head_mm<<<128 + QROW, 256, 8 * HH * 4, stream>>>(
            T1, HH, ln1w + l * HH, ln1b + l * HH,
            f1_w + (size_t)l * 4 * HH * HH, f1_b + l * 4 * HH,
            nullptr, nullptr, nullptr, F, 4 * HH, 16, 1,
            Psi, A, Mask, 128, arow);
        arow += QROW;
        // t2 = LN(t1,ln1) + (f @ W2^T + b2) (J=512, K=2048, G=64)
        head_mm<<<128 + QROW, 256, 0, stream>>>(
            F, 4 * HH, nullptr, nullptr,
            f2_w + (size_t)l * HH * 4 * HH, f2_b + l * HH,
            T1, ln1w + l * HH, ln1b + l * HH, T, HH, 64, 0,
            Psi, A, Mask, 128, arow);
        arow += QROW;
    }
    // ---- tail: LN chain + p1 + preds (block 0) + remaining store rows ----
    {
        int qrem = NROWS - arow;   // 1252
        tail_kernel<<<1 + qrem, 256, 0, stream>>>(
            T, ln2w, ln2b, nAw, nAb, nBw, nBb, p1w, p1b, p2w, p2b,
            preds, Psi, A, Mask, arow);
    }
}